// Round 15
// baseline (483.637 us; speedup 1.0000x reference)
//
#include <hip/hip_runtime.h>

// ---------------------------------------------------------------------------
// MultiheadAttentionWithAttention: y = Wo(attn(Wq q, Wk k, Wv v)) + bo,
// plus head-mean attention map. B=4, T=T_MEM=1024, C=1024, H=16, hd=64.
//
// ROUND 15 = barrier-free attention rewrite (wave-per-head two-pass flash):
//   Block (1024 thr) = (b, 16 q-rows); wave w = head w. NO barriers in the
//   head loop (the 3-barrier shared-score structure stalled 90%: r14 counters
//   MfmaUtil 5.5 / VALU 23 / 122us). Per wave:
//     pass1: stream K (L2-resident), swapped QK^T (r14-proven addresses),
//            per-lane online (m,l), 2-shfl merge.
//     pass2: re-stream K; P = exp(s-m)*inv via pk_bf16 on expf outputs
//            (r14-proven safe; r13 lesson: never feed MFMA results to asm);
//            P relayed through a WAVE-PRIVATE LDS strip (ds_write -> same-
//            wave ds_read, compiler lgkmcnt, no barrier) into PV A-frags;
//            V^T B-frags identical to r14 P3; head-mean via atomicAdd into
//            block-shared fp32 AM[1024][17] (pad 17 spreads banks).
//   attm written fp32 DIRECTLY (block covers all 16 heads) -> mean2 deleted.
//   XCD swizzle: bid%8 -> XCD; b = (bid&7)>>1 so each XCD works ONE b
//   (K+V working set 4MB = its L2). K read 2x (~1.5GB L2 ~43us floor) in
//   exchange for zero barrier stall.
//   O accum = 4 named f32x4x4 regs, never live across a barrier (r9/r12
//   spill class impossible).
//
// Pipeline: cvt -> gemm_qkv -> transpose_v -> attn_flash -> gemm_out.
// ws layout (MB), 56 MB total:
//   [0,24)  xin bf16 (q,k,v)  -> [16,24) Vt after transpose (over dead v)
//   [24,32) W bf16 in order Wo,Wq,Wk,Wv
//   [32,56) Qp,Kp,Vp          -> Vp slot [48,56) becomes Ybf after transpose
// ---------------------------------------------------------------------------

typedef __attribute__((ext_vector_type(8))) short s16x8;
typedef __attribute__((ext_vector_type(4))) float f32x4;
typedef __attribute__((ext_vector_type(4))) unsigned short u16x4;

#define N_EMBD 1024
#define NH 16
#define BT 4096  // B*T flattened rows

#if __has_builtin(__builtin_amdgcn_global_load_lds)
#define HAVE_GLL 1
#define GLDS16(g, l)                                                              \
  __builtin_amdgcn_global_load_lds((__attribute__((address_space(1))) void*)(g), \
                                   (__attribute__((address_space(3))) void*)(l), 16, 0, 0)
#else
#define HAVE_GLL 0
#endif

static __device__ __forceinline__ unsigned short f2bf(float f) {
  unsigned int u = __builtin_bit_cast(unsigned int, f);
  u += 0x7FFFu + ((u >> 16) & 1u);  // RNE
  return (unsigned short)(u >> 16);
}
static __device__ __forceinline__ float bf2f(unsigned short h) {
  return __builtin_bit_cast(float, ((unsigned int)h) << 16);
}
// HW packed f32->bf16, 1 instr per 2 values. ONLY feed VALU-produced values
// (e.g. __expf outputs) — direct MFMA consumers corrupt data (r13 lesson).
static __device__ __forceinline__ unsigned int pk_bf16(float lo, float hi) {
  unsigned int r;
  asm("v_cvt_pk_bf16_f32 %0, %1, %2" : "=v"(r) : "v"(lo), "v"(hi));
  return r;
}

// ---------------- fp32 -> bf16 converts (batched) ----------------
__global__ __launch_bounds__(256) void cvt_in3(const float* __restrict__ q,
                                               const float* __restrict__ k,
                                               const float* __restrict__ v,
                                               unsigned short* __restrict__ out) {
  const int z = blockIdx.z;
  const float* src = (z == 0) ? q : (z == 1 ? k : v);
  int i = (blockIdx.x * 256 + threadIdx.x) * 4;
  float4 val = *(const float4*)(src + i);
  u16x4 o;
  o[0] = f2bf(val.x);
  o[1] = f2bf(val.y);
  o[2] = f2bf(val.z);
  o[3] = f2bf(val.w);
  *(u16x4*)(out + (size_t)z * BT * N_EMBD + i) = o;
}

__global__ __launch_bounds__(256) void cvt_w4(const float* __restrict__ wo,
                                              const float* __restrict__ wq,
                                              const float* __restrict__ wk,
                                              const float* __restrict__ wv,
                                              unsigned short* __restrict__ out) {
  const int z = blockIdx.z;
  const float* src = (z == 0) ? wo : (z == 1 ? wq : (z == 2 ? wk : wv));
  const float scale = (z == 1) ? 0.125f : 1.0f;  // fold 1/sqrt(hd) into Wq
  int i = (blockIdx.x * 256 + threadIdx.x) * 4;
  float4 val = *(const float4*)(src + i);
  u16x4 o;
  o[0] = f2bf(val.x * scale);
  o[1] = f2bf(val.y * scale);
  o[2] = f2bf(val.z * scale);
  o[3] = f2bf(val.w * scale);
  *(u16x4*)(out + (size_t)z * N_EMBD * N_EMBD + i) = o;
}

// ---------------- 128x128 bf16 MFMA tile: C = A * B^T + bias ----------------
template <bool F32OUT>
static __device__ __forceinline__ void gemm_bt_tile(const unsigned short* __restrict__ A,
                                                    const unsigned short* __restrict__ B,
                                                    const float* __restrict__ bias, float bscale,
                                                    void* __restrict__ Cout,
                                                    int m0, int n0, int N, int K,
                                                    unsigned short* Al, unsigned short* Bl) {
  const int tid = threadIdx.x;
  const int l = tid & 63, w = tid >> 6;
  const int wr = w >> 1, wc = w & 1;
  const int l15 = l & 15, l4 = l >> 4;
  const int srow = tid >> 3;          // staging row within 32-row chunk
  const int skk = (tid & 7) * 8;      // staging k offset (16B)
  f32x4 acc[4][4] = {};
  for (int k0 = 0; k0 < K; k0 += 64) {
#if HAVE_GLL
#pragma unroll
    for (int i = 0; i < 4; ++i) {
      GLDS16(&A[(size_t)(m0 + i * 32 + srow) * K + k0 + skk], Al + i * 2048 + w * 512);
      GLDS16(&B[(size_t)(n0 + i * 32 + srow) * K + k0 + skk], Bl + i * 2048 + w * 512);
    }
#else
#pragma unroll
    for (int i = 0; i < 4; ++i) {
      int row = i * 32 + srow;
      *(s16x8*)&Al[row * 64 + skk] = *(const s16x8*)&A[(size_t)(m0 + row) * K + k0 + skk];
      *(s16x8*)&Bl[row * 64 + skk] = *(const s16x8*)&B[(size_t)(n0 + row) * K + k0 + skk];
    }
#endif
    __syncthreads();
#pragma unroll
    for (int kf = 0; kf < 2; ++kf) {
      s16x8 af[4], bfr[4];
#pragma unroll
      for (int mi = 0; mi < 4; ++mi)
        af[mi] = *(const s16x8*)&Al[(wr * 64 + mi * 16 + l15) * 64 + kf * 32 + l4 * 8];
#pragma unroll
      for (int nj = 0; nj < 4; ++nj)
        bfr[nj] = *(const s16x8*)&Bl[(wc * 64 + nj * 16 + l15) * 64 + kf * 32 + l4 * 8];
#pragma unroll
      for (int mi = 0; mi < 4; ++mi) {
#pragma unroll
        for (int nj = 0; nj < 4; ++nj)
          acc[mi][nj] =
              __builtin_amdgcn_mfma_f32_16x16x32_bf16(af[mi], bfr[nj], acc[mi][nj], 0, 0, 0);
      }
    }
    __syncthreads();
  }
#pragma unroll
  for (int nj = 0; nj < 4; ++nj) {
    int col = n0 + wc * 64 + nj * 16 + l15;
    float bv = bias[col] * bscale;
#pragma unroll
    for (int mi = 0; mi < 4; ++mi) {
#pragma unroll
      for (int r = 0; r < 4; ++r) {
        int row = m0 + wr * 64 + mi * 16 + l4 * 4 + r;
        float v = acc[mi][nj][r] + bv;
        if constexpr (F32OUT)
          ((float*)Cout)[(size_t)row * N + col] = v;
        else
          ((unsigned short*)Cout)[(size_t)row * N + col] = f2bf(v);
      }
    }
  }
}

// Batched QKV projection: grid.z selects q/k/v. Weights ordered Wo,Wq,Wk,Wv.
__global__ __launch_bounds__(256) void gemm_qkv(const unsigned short* __restrict__ Xin,
                                                const unsigned short* __restrict__ Wbf,
                                                const float* __restrict__ bq,
                                                const float* __restrict__ bk,
                                                const float* __restrict__ bv,
                                                unsigned short* __restrict__ Cout) {
  __shared__ unsigned short Al[128 * 64];
  __shared__ unsigned short Bl[128 * 64];
  const int z = blockIdx.z;
  const float* bias = (z == 0) ? bq : (z == 1 ? bk : bv);
  const float bscale = (z == 0) ? 0.125f : 1.0f;
  gemm_bt_tile<false>(Xin + (size_t)z * BT * N_EMBD,
                      Wbf + (size_t)(1 + z) * N_EMBD * N_EMBD, bias, bscale,
                      Cout + (size_t)z * BT * N_EMBD, blockIdx.x * 128, blockIdx.y * 128,
                      N_EMBD, N_EMBD, Al, Bl);
}

__global__ __launch_bounds__(256) void gemm_out(const unsigned short* __restrict__ Ybf,
                                                const unsigned short* __restrict__ Wo,
                                                const float* __restrict__ bo,
                                                float* __restrict__ Cout) {
  __shared__ unsigned short Al[128 * 64];
  __shared__ unsigned short Bl[128 * 64];
  gemm_bt_tile<true>(Ybf, Wo, bo, 1.0f, Cout, blockIdx.x * 128, blockIdx.y * 128, N_EMBD, N_EMBD,
                     Al, Bl);
}

// ---------------- V transpose: Vp[b,t,h*64+d] -> Vt[(b,h),d,t] ----------------
__global__ __launch_bounds__(256) void transpose_v(const unsigned short* __restrict__ Vp,
                                                   unsigned short* __restrict__ Vt) {
  __shared__ unsigned short tile[64][65];
  const int t0 = blockIdx.x * 64, h = blockIdx.y, b = blockIdx.z;
  const int r = threadIdx.x >> 2, c0 = (threadIdx.x & 3) * 16;
  const unsigned short* src = Vp + (size_t)(b * 1024 + t0 + r) * 1024 + h * 64 + c0;
#pragma unroll
  for (int j = 0; j < 16; ++j) tile[r][c0 + j] = src[j];
  __syncthreads();
  unsigned short* dst = Vt + (size_t)((b * 16 + h) * 64 + r) * 1024 + t0 + c0;
#pragma unroll
  for (int j = 0; j < 16; ++j) dst[j] = tile[c0 + j][r];
}

// ---------------- barrier-free attention: wave = head, two-pass ------------
// Block (1024 thr) = (b, 16 q-rows q0..q0+15); wave w = head w (16 heads).
// pass1: per-lane online (m,l) over the lane's k-subset, merged via
//        shfl_xor(16,32) -> exact row (m,l) per q=l15.
// pass2: per 32k chunk: 2x swapped QK^T mfma-pairs -> P = exp(s-m)*inv ->
//        bf16 (pk_bf16 on expf outputs) -> wave-private strip [16q][40] ->
//        b128 A-frag -> 4 PV mfma vs V^T; head-mean p/16 atomicAdd into
//        AM[k][17-padded q] (fp32).
// Epilogue: Ybf per wave; barrier; AM -> attm fp32 (block = all 16 heads).
__global__ __launch_bounds__(1024, 4) void attn_flash(const unsigned short* __restrict__ Qp,
                                                      const unsigned short* __restrict__ Kp,
                                                      const unsigned short* __restrict__ Vt,
                                                      unsigned short* __restrict__ Ybf,
                                                      float* __restrict__ attm) {
  __shared__ float AM[1024 * 17];                         // 69.6 KB head-mean accum
  __shared__ __align__(16) unsigned short strip[16][640]; // 20 KB per-wave P relay
  const int tid = threadIdx.x;
  const int w = tid >> 6, l = tid & 63;
  const int l15 = l & 15, l4 = l >> 4;
  const int bid = blockIdx.x;
  const int g = bid & 7;                    // XCD (round-robin dispatch)
  const int b = g >> 1;                     // each XCD works ONE b (L2 fit)
  const int qt = (g & 1) * 32 + (bid >> 3); // bijective (b,qt) cover
  const int q0 = qt * 16;
  const int h = w;

  // zero head-mean accumulator
  for (int i = tid; i < 1024 * 17; i += 1024) AM[i] = 0.f;
  __syncthreads();

  // Q fragments (B-operand of swapped QK^T): rows q0+l15, head h
  const unsigned short* qbase = Qp + (size_t)(b * 1024 + q0 + l15) * 1024 + h * 64 + l4 * 8;
  s16x8 aq0 = *(const s16x8*)qbase;
  s16x8 aq1 = *(const s16x8*)(qbase + 32);
  const unsigned short* kbase = Kp + (size_t)(b * 1024 + l15) * 1024 + h * 64 + l4 * 8;

  // ---- pass 1: per-lane online (m, l) ----
  float m = -3.4e38f, lden = 0.f;
#pragma unroll 4
  for (int nt = 0; nt < 64; ++nt) {
    const unsigned short* kb = kbase + (size_t)(nt * 16) * 1024;
    f32x4 s = {};
    s = __builtin_amdgcn_mfma_f32_16x16x32_bf16(*(const s16x8*)kb, aq0, s, 0, 0, 0);
    s = __builtin_amdgcn_mfma_f32_16x16x32_bf16(*(const s16x8*)(kb + 32), aq1, s, 0, 0, 0);
    float t = fmaxf(fmaxf(s[0], s[1]), fmaxf(s[2], s[3]));
    if (t > m) {
      lden *= __expf(m - t);
      m = t;
    }
    lden += ((__expf(s[0] - m) + __expf(s[1] - m)) + (__expf(s[2] - m) + __expf(s[3] - m)));
  }
  // merge (m,l) across the 4 l4-groups sharing q=l15
  {
    float mo = __shfl_xor(m, 16), lo = __shfl_xor(lden, 16);
    float mn = fmaxf(m, mo);
    lden = lden * __expf(m - mn) + lo * __expf(mo - mn);
    m = mn;
    mo = __shfl_xor(m, 32);
    lo = __shfl_xor(lden, 32);
    mn = fmaxf(m, mo);
    lden = lden * __expf(m - mn) + lo * __expf(mo - mn);
    m = mn;
  }
  const float inv = 1.0f / lden;

  // ---- pass 2: P + PV + head-mean, zero barriers ----
  f32x4 o0 = {}, o1 = {}, o2 = {}, o3 = {};  // O[dt]: row q=l4*4+rr, col d=dt*16+l15
  unsigned short* const st = strip[w];
  const unsigned short* vbase = Vt + (size_t)((b * 16 + h) * 64 + l15) * 1024 + l4 * 8;
#pragma unroll 1
  for (int c = 0; c < 32; ++c) {
#pragma unroll
    for (int o = 0; o < 2; ++o) {
      const int nt = c * 2 + o;
      const unsigned short* kb = kbase + (size_t)(nt * 16) * 1024;
      f32x4 s = {};
      s = __builtin_amdgcn_mfma_f32_16x16x32_bf16(*(const s16x8*)kb, aq0, s, 0, 0, 0);
      s = __builtin_amdgcn_mfma_f32_16x16x32_bf16(*(const s16x8*)(kb + 32), aq1, s, 0, 0, 0);
      float p0 = __expf(s[0] - m) * inv;
      float p1 = __expf(s[1] - m) * inv;
      float p2 = __expf(s[2] - m) * inv;
      float p3 = __expf(s[3] - m) * inv;
      uint2 pk;
      pk.x = pk_bf16(p0, p1);  // expf outputs -> safe for asm (r14-proven)
      pk.y = pk_bf16(p2, p3);
      *(uint2*)&st[l15 * 40 + o * 16 + l4 * 4] = pk;
      const int kg = nt * 16 + l4 * 4;
      atomicAdd(&AM[(kg + 0) * 17 + l15], p0 * 0.0625f);
      atomicAdd(&AM[(kg + 1) * 17 + l15], p1 * 0.0625f);
      atomicAdd(&AM[(kg + 2) * 17 + l15], p2 * 0.0625f);
      atomicAdd(&AM[(kg + 3) * 17 + l15], p3 * 0.0625f);
    }
    // PV: A-frag = P[q=l15][k_local=l4*8..+8] (b128 from own strip)
    s16x8 pa = *(const s16x8*)&st[l15 * 40 + l4 * 8];
    const unsigned short* vb = vbase + c * 32;
    o0 = __builtin_amdgcn_mfma_f32_16x16x32_bf16(pa, *(const s16x8*)vb, o0, 0, 0, 0);
    o1 = __builtin_amdgcn_mfma_f32_16x16x32_bf16(pa, *(const s16x8*)(vb + 16 * 1024), o1, 0, 0, 0);
    o2 = __builtin_amdgcn_mfma_f32_16x16x32_bf16(pa, *(const s16x8*)(vb + 32 * 1024), o2, 0, 0, 0);
    o3 = __builtin_amdgcn_mfma_f32_16x16x32_bf16(pa, *(const s16x8*)(vb + 48 * 1024), o3, 0, 0, 0);
  }

  // ---- Ybf write (P was normalized -> O final) ----
  unsigned short* yb = Ybf + (size_t)(b * 1024 + q0 + l4 * 4) * 1024 + h * 64 + l15;
#pragma unroll
  for (int rr = 0; rr < 4; ++rr) {
    yb[(size_t)rr * 1024] = f2bf(o0[rr]);
    yb[(size_t)rr * 1024 + 16] = f2bf(o1[rr]);
    yb[(size_t)rr * 1024 + 32] = f2bf(o2[rr]);
    yb[(size_t)rr * 1024 + 48] = f2bf(o3[rr]);
  }

  __syncthreads();  // all waves' atomics complete
  // ---- attm write: thread (q = tid>>6, c = tid&63) -> k = c*16..+16 ----
  {
    const int q = tid >> 6, c = tid & 63;
    float* outp = attm + (size_t)(b * 1024 + q0 + q) * 1024 + c * 16;
#pragma unroll
    for (int i = 0; i < 16; ++i) outp[i] = AM[(c * 16 + i) * 17 + q];
  }
}

// ---------------------------------------------------------------------------
extern "C" void kernel_launch(void* const* d_in, const int* in_sizes, int n_in, void* d_out,
                              int out_size, void* d_ws, size_t ws_size, hipStream_t stream) {
  const float* q_in = (const float*)d_in[0];
  const float* k_in = (const float*)d_in[1];
  const float* v_in = (const float*)d_in[2];
  const float* Wq = (const float*)d_in[3];
  const float* bq = (const float*)d_in[4];
  const float* Wk = (const float*)d_in[5];
  const float* bk = (const float*)d_in[6];
  const float* Wv = (const float*)d_in[7];
  const float* bv = (const float*)d_in[8];
  const float* Wo = (const float*)d_in[9];
  const float* bo = (const float*)d_in[10];

  float* out_y = (float*)d_out;
  float* out_att = out_y + (size_t)BT * N_EMBD;

  char* ws = (char*)d_ws;
  const size_t MB = 1024 * 1024;
  unsigned short* xin_bf = (unsigned short*)(ws);           // 3 x 8MB (q,k,v inputs bf16)
  unsigned short* W_bf = (unsigned short*)(ws + 24 * MB);   // Wo,Wq,Wk,Wv bf16
  unsigned short* Qp = (unsigned short*)(ws + 32 * MB);
  unsigned short* Kp = Qp + (size_t)BT * N_EMBD;
  unsigned short* Vp = Kp + (size_t)BT * N_EMBD;
  unsigned short* Vt = (unsigned short*)(ws + 16 * MB);     // over dead v xin
  unsigned short* Ybf = Vp;                                 // over dead Vp (after transpose_v)

  const int NIN = BT * N_EMBD;     // 4M
  const int NW = N_EMBD * N_EMBD;  // 1M

  cvt_in3<<<dim3(NIN / 1024, 1, 3), 256, 0, stream>>>(q_in, k_in, v_in, xin_bf);
  cvt_w4<<<dim3(NW / 1024, 1, 4), 256, 0, stream>>>(Wo, Wq, Wk, Wv, W_bf);

  gemm_qkv<<<dim3(BT / 128, N_EMBD / 128, 3), 256, 0, stream>>>(xin_bf, W_bf, bq, bk, bv, Qp);
  transpose_v<<<dim3(16, 16, 4), 256, 0, stream>>>(Vp, Vt);
  attn_flash<<<256, 1024, 0, stream>>>(Qp, Kp, Vt, Ybf, out_att);
  gemm_out<<<dim3(BT / 128, N_EMBD / 128), 256, 0, stream>>>(Ybf, W_bf, bo, out_y);
}

// Round 16
// 223.227 us; speedup vs baseline: 2.1666x; 2.1666x over previous
//
#include <hip/hip_runtime.h>
#include <hip/hip_fp16.h>

// ---------------------------------------------------------------------------
// MultiheadAttentionWithAttention: y = Wo(attn(Wq q, Wk k, Wv v)) + bo,
// plus head-mean attention map. B=4, T=T_MEM=1024, C=1024, H=16, hd=64.
//
// ROUND 16 = r14 (passing, 122us attn) with the global-max pass removed:
//   exact softmax via PER-SEGMENT scales. P1 computes scores + wave-local
//   row max m_w (2 shfls, in-register); P2-own re-reads ONLY its own raw
//   stores (same-wave LDS, no barrier), exp(s - m_w), packs e-values
//   (pk_bf16 on expf outputs - r14-proven), publishes (m_w, l_w) float2.
//   ONE barrier. P3: each PV fragment (32k) lies inside ONE producing
//   wave's 128k segment -> accumulate ys[8] per-segment (static idx, never
//   across a barrier), combine y = sum_w ys[w] * e^(m_w-M) / L per row.
//   Exact (not approximate) softmax. Barriers/iter 3 -> 2; RedM pass gone;
//   P2 no longer waits on other waves' P1; PV = 8 short MFMA chains.
//   r15 lesson: LDS atomics + serial online chains are worse than barriers
//   (400us). r13 lesson: never feed MFMA results to inline asm. r9/r12
//   lesson: no large arrays live across __syncthreads().
//
// Pipeline (bf16 MFMA, fp32 accum):
//   1. cvt_in3 / cvt_w4: fp32->bf16 (Wq pre-scaled by 1/8)
//   2. QKV projections: batched 128x128 gemm_bt with global_load_lds staging
//   3. transpose V to [b,h,d,t]
//   4. attn_ph2: 1024 thr = 2 teams x 8 waves; block = (b, 32 q-rows, hg)
//   5. mean2: attm = partial[hg0] + partial[hg1]  (fp32)
//   6. output projection -> fp32 d_out
//
// ws layout (MB), 56 MB total:
//   [0,24)  xin bf16 (q,k,v)  -> after gemm_qkv: [0,16) Pmean, [16,24) Vt
//   [24,32) W bf16 in order Wo,Wq,Wk,Wv
//   [32,56) Qp,Kp,Vp          -> Vp slot [48,56) becomes Ybf after transpose
// ---------------------------------------------------------------------------

typedef __attribute__((ext_vector_type(8))) short s16x8;
typedef __attribute__((ext_vector_type(4))) float f32x4;
typedef __attribute__((ext_vector_type(4))) unsigned short u16x4;

#define N_EMBD 1024
#define NH 16
#define BT 4096  // B*T flattened rows
#define STR 1032 // LDS score row stride (elements)

#if __has_builtin(__builtin_amdgcn_global_load_lds)
#define HAVE_GLL 1
#define GLDS16(g, l)                                                              \
  __builtin_amdgcn_global_load_lds((__attribute__((address_space(1))) void*)(g), \
                                   (__attribute__((address_space(3))) void*)(l), 16, 0, 0)
#else
#define HAVE_GLL 0
#endif

static __device__ __forceinline__ unsigned short f2bf(float f) {
  unsigned int u = __builtin_bit_cast(unsigned int, f);
  u += 0x7FFFu + ((u >> 16) & 1u);  // RNE
  return (unsigned short)(u >> 16);
}
static __device__ __forceinline__ float bf2f(unsigned short h) {
  return __builtin_bit_cast(float, ((unsigned int)h) << 16);
}
// HW packed f32->bf16, 1 instr per 2 values. ONLY feed VALU-produced values
// (e.g. __expf outputs) — direct MFMA consumers corrupt data (r13 lesson).
static __device__ __forceinline__ unsigned int pk_bf16(float lo, float hi) {
  unsigned int r;
  asm("v_cvt_pk_bf16_f32 %0, %1, %2" : "=v"(r) : "v"(lo), "v"(hi));
  return r;
}

// ---------------- fp32 -> bf16 converts (batched) ----------------
__global__ __launch_bounds__(256) void cvt_in3(const float* __restrict__ q,
                                               const float* __restrict__ k,
                                               const float* __restrict__ v,
                                               unsigned short* __restrict__ out) {
  const int z = blockIdx.z;
  const float* src = (z == 0) ? q : (z == 1 ? k : v);
  int i = (blockIdx.x * 256 + threadIdx.x) * 4;
  float4 val = *(const float4*)(src + i);
  u16x4 o;
  o[0] = f2bf(val.x);
  o[1] = f2bf(val.y);
  o[2] = f2bf(val.z);
  o[3] = f2bf(val.w);
  *(u16x4*)(out + (size_t)z * BT * N_EMBD + i) = o;
}

__global__ __launch_bounds__(256) void cvt_w4(const float* __restrict__ wo,
                                              const float* __restrict__ wq,
                                              const float* __restrict__ wk,
                                              const float* __restrict__ wv,
                                              unsigned short* __restrict__ out) {
  const int z = blockIdx.z;
  const float* src = (z == 0) ? wo : (z == 1 ? wq : (z == 2 ? wk : wv));
  const float scale = (z == 1) ? 0.125f : 1.0f;  // fold 1/sqrt(hd) into Wq
  int i = (blockIdx.x * 256 + threadIdx.x) * 4;
  float4 val = *(const float4*)(src + i);
  u16x4 o;
  o[0] = f2bf(val.x * scale);
  o[1] = f2bf(val.y * scale);
  o[2] = f2bf(val.z * scale);
  o[3] = f2bf(val.w * scale);
  *(u16x4*)(out + (size_t)z * N_EMBD * N_EMBD + i) = o;
}

// ---------------- 128x128 bf16 MFMA tile: C = A * B^T + bias ----------------
template <bool F32OUT>
static __device__ __forceinline__ void gemm_bt_tile(const unsigned short* __restrict__ A,
                                                    const unsigned short* __restrict__ B,
                                                    const float* __restrict__ bias, float bscale,
                                                    void* __restrict__ Cout,
                                                    int m0, int n0, int N, int K,
                                                    unsigned short* Al, unsigned short* Bl) {
  const int tid = threadIdx.x;
  const int l = tid & 63, w = tid >> 6;
  const int wr = w >> 1, wc = w & 1;
  const int l15 = l & 15, l4 = l >> 4;
  const int srow = tid >> 3;          // staging row within 32-row chunk
  const int skk = (tid & 7) * 8;      // staging k offset (16B)
  f32x4 acc[4][4] = {};
  for (int k0 = 0; k0 < K; k0 += 64) {
#if HAVE_GLL
#pragma unroll
    for (int i = 0; i < 4; ++i) {
      GLDS16(&A[(size_t)(m0 + i * 32 + srow) * K + k0 + skk], Al + i * 2048 + w * 512);
      GLDS16(&B[(size_t)(n0 + i * 32 + srow) * K + k0 + skk], Bl + i * 2048 + w * 512);
    }
#else
#pragma unroll
    for (int i = 0; i < 4; ++i) {
      int row = i * 32 + srow;
      *(s16x8*)&Al[row * 64 + skk] = *(const s16x8*)&A[(size_t)(m0 + row) * K + k0 + skk];
      *(s16x8*)&Bl[row * 64 + skk] = *(const s16x8*)&B[(size_t)(n0 + row) * K + k0 + skk];
    }
#endif
    __syncthreads();
#pragma unroll
    for (int kf = 0; kf < 2; ++kf) {
      s16x8 af[4], bfr[4];
#pragma unroll
      for (int mi = 0; mi < 4; ++mi)
        af[mi] = *(const s16x8*)&Al[(wr * 64 + mi * 16 + l15) * 64 + kf * 32 + l4 * 8];
#pragma unroll
      for (int nj = 0; nj < 4; ++nj)
        bfr[nj] = *(const s16x8*)&Bl[(wc * 64 + nj * 16 + l15) * 64 + kf * 32 + l4 * 8];
#pragma unroll
      for (int mi = 0; mi < 4; ++mi) {
#pragma unroll
        for (int nj = 0; nj < 4; ++nj)
          acc[mi][nj] =
              __builtin_amdgcn_mfma_f32_16x16x32_bf16(af[mi], bfr[nj], acc[mi][nj], 0, 0, 0);
      }
    }
    __syncthreads();
  }
#pragma unroll
  for (int nj = 0; nj < 4; ++nj) {
    int col = n0 + wc * 64 + nj * 16 + l15;
    float bv = bias[col] * bscale;
#pragma unroll
    for (int mi = 0; mi < 4; ++mi) {
#pragma unroll
      for (int r = 0; r < 4; ++r) {
        int row = m0 + wr * 64 + mi * 16 + l4 * 4 + r;
        float v = acc[mi][nj][r] + bv;
        if constexpr (F32OUT)
          ((float*)Cout)[(size_t)row * N + col] = v;
        else
          ((unsigned short*)Cout)[(size_t)row * N + col] = f2bf(v);
      }
    }
  }
}

// Batched QKV projection: grid.z selects q/k/v. Weights ordered Wo,Wq,Wk,Wv.
__global__ __launch_bounds__(256) void gemm_qkv(const unsigned short* __restrict__ Xin,
                                                const unsigned short* __restrict__ Wbf,
                                                const float* __restrict__ bq,
                                                const float* __restrict__ bk,
                                                const float* __restrict__ bv,
                                                unsigned short* __restrict__ Cout) {
  __shared__ unsigned short Al[128 * 64];
  __shared__ unsigned short Bl[128 * 64];
  const int z = blockIdx.z;
  const float* bias = (z == 0) ? bq : (z == 1 ? bk : bv);
  const float bscale = (z == 0) ? 0.125f : 1.0f;
  gemm_bt_tile<false>(Xin + (size_t)z * BT * N_EMBD,
                      Wbf + (size_t)(1 + z) * N_EMBD * N_EMBD, bias, bscale,
                      Cout + (size_t)z * BT * N_EMBD, blockIdx.x * 128, blockIdx.y * 128,
                      N_EMBD, N_EMBD, Al, Bl);
}

__global__ __launch_bounds__(256) void gemm_out(const unsigned short* __restrict__ Ybf,
                                                const unsigned short* __restrict__ Wo,
                                                const float* __restrict__ bo,
                                                float* __restrict__ Cout) {
  __shared__ unsigned short Al[128 * 64];
  __shared__ unsigned short Bl[128 * 64];
  gemm_bt_tile<true>(Ybf, Wo, bo, 1.0f, Cout, blockIdx.x * 128, blockIdx.y * 128, N_EMBD, N_EMBD,
                     Al, Bl);
}

// ---------------- V transpose: Vp[b,t,h*64+d] -> Vt[(b,h),d,t] ----------------
__global__ __launch_bounds__(256) void transpose_v(const unsigned short* __restrict__ Vp,
                                                   unsigned short* __restrict__ Vt) {
  __shared__ unsigned short tile[64][65];
  const int t0 = blockIdx.x * 64, h = blockIdx.y, b = blockIdx.z;
  const int r = threadIdx.x >> 2, c0 = (threadIdx.x & 3) * 16;
  const unsigned short* src = Vp + (size_t)(b * 1024 + t0 + r) * 1024 + h * 64 + c0;
#pragma unroll
  for (int j = 0; j < 16; ++j) tile[r][c0 + j] = src[j];
  __syncthreads();
  unsigned short* dst = Vt + (size_t)((b * 16 + h) * 64 + r) * 1024 + t0 + c0;
#pragma unroll
  for (int j = 0; j < 16; ++j) dst[j] = tile[c0 + j][r];
}

// ---------------- fused attention: per-segment exact softmax ----------
// Block (1024 thr) = (b, hg, 32 q-rows); team tm = tid>>9 = head hg*8+it*2+tm.
// P1: swapped QK^T — wave w4 covers gn = w4*8+nt (K frag feeds both q-groups);
//     raw bf16 u16x4 stores (software RNE); wave-local row max m0/m1 via
//     shfl(16,32). NO cross-wave max, NO barrier.
// P2-own: re-read OWN raw stores (same-wave LDS ordering), exp(s - m_w),
//     pack via pk_bf16 (expf outputs), writeback; row-sum ps via shfls;
//     publish RedSM[row][w4] = (m_w, l_w). ONE barrier.
// P3: wave w4 -> (qgw=w4>>2, dtw=w4&3). Each PV fragment (32k) is inside one
//     producing wave's 128k segment -> ys[8] per-segment accumulators;
//     y(row) = sum_w ys[w] * e^(m_w - M_row) / L_row (exact). amean fused
//     with per-segment scales sA/sB. Barrier E ends the iteration.
__global__ __launch_bounds__(1024, 4) void attn_ph2(const unsigned short* __restrict__ Qp,
                                                    const unsigned short* __restrict__ Kp,
                                                    const unsigned short* __restrict__ Vt,
                                                    unsigned short* __restrict__ Ybf,
                                                    unsigned short* __restrict__ Pmean) {
  __shared__ __align__(16) unsigned short S2[2][32 * STR];  // per-team scores/probs (132KB)
  __shared__ float2 RedSM[2][32][8];                        // (m_w, l_w) per row x wave (2KB)
  const int tid = threadIdx.x;
  const int tm = tid >> 9;     // team 0/1
  const int ttid = tid & 511;  // id within team
  const int w4 = ttid >> 6;    // wave within team, 0..7
  const int l = tid & 63;
  const int l15 = l & 15, l4 = l >> 4;
  const int qgw = w4 >> 2;     // P3: wave's q-group
  const int dtw = w4 & 3;      // P3: wave's d-tile / amean k-quarter

  const int bid = blockIdx.x;
  const int grp = bid & 7, qt = bid >> 3;  // grp -> XCD (round-robin dispatch)
  const int b = grp >> 1, hg = grp & 1;
  const int q0 = qt * 32;

  // head-mean accumulator: cell j = kk*4+e2 packs
  // k = dtw*256 + kk*32 + l4*8 + {2e2, 2e2+1}, q = qgw*16 + l15.
  __half2 am[32];
#pragma unroll
  for (int j = 0; j < 32; ++j) am[j] = __float2half2_rn(0.f);

#pragma unroll 1
  for (int it = 0; it < 4; ++it) {
    const int h = hg * 8 + it * 2 + tm;
    // ---- P1: swapped QK^T; K fragment shared by both q-groups ----
    const unsigned short* qb0 = Qp + (size_t)(b * 1024 + q0 + l15) * 1024 + h * 64 + l4 * 8;
    const unsigned short* qb1 = qb0 + (size_t)16 * 1024;
    s16x8 aq00 = *(const s16x8*)qb0;
    s16x8 aq01 = *(const s16x8*)(qb0 + 32);
    s16x8 aq10 = *(const s16x8*)qb1;
    s16x8 aq11 = *(const s16x8*)(qb1 + 32);
    float m0 = -3.4e38f, m1 = -3.4e38f;
    __builtin_amdgcn_s_setprio(1);
#pragma unroll
    for (int nt = 0; nt < 8; ++nt) {
      int gn = w4 * 8 + nt;
      const unsigned short* kb = Kp + (size_t)(b * 1024 + gn * 16 + l15) * 1024 + h * 64 + l4 * 8;
      s16x8 kf0 = *(const s16x8*)kb;
      s16x8 kf1 = *(const s16x8*)(kb + 32);
      f32x4 s0 = {}, s1 = {};
      s0 = __builtin_amdgcn_mfma_f32_16x16x32_bf16(kf0, aq00, s0, 0, 0, 0);
      s0 = __builtin_amdgcn_mfma_f32_16x16x32_bf16(kf1, aq01, s0, 0, 0, 0);
      s1 = __builtin_amdgcn_mfma_f32_16x16x32_bf16(kf0, aq10, s1, 0, 0, 0);
      s1 = __builtin_amdgcn_mfma_f32_16x16x32_bf16(kf1, aq11, s1, 0, 0, 0);
      u16x4 p0, p1;
#pragma unroll
      for (int rr = 0; rr < 4; ++rr) {
        m0 = fmaxf(m0, s0[rr]);
        p0[rr] = f2bf(s0[rr]);
        m1 = fmaxf(m1, s1[rr]);
        p1[rr] = f2bf(s1[rr]);
      }
      *(u16x4*)&S2[tm][l15 * STR + gn * 16 + l4 * 4] = p0;
      *(u16x4*)&S2[tm][(16 + l15) * STR + gn * 16 + l4 * 4] = p1;
    }
    __builtin_amdgcn_s_setprio(0);
    m0 = fmaxf(m0, __shfl_xor(m0, 16));
    m0 = fmaxf(m0, __shfl_xor(m0, 32));
    m1 = fmaxf(m1, __shfl_xor(m1, 16));
    m1 = fmaxf(m1, __shfl_xor(m1, 32));

    // ---- P2-own: exp with wave-local max; re-read own stores, no barrier ----
    float ps0 = 0.f, ps1 = 0.f;
#pragma unroll
    for (int nt = 0; nt < 8; ++nt) {
      int gn = w4 * 8 + nt;
      unsigned short* sp0 = &S2[tm][l15 * STR + gn * 16 + l4 * 4];
      unsigned short* sp1 = &S2[tm][(16 + l15) * STR + gn * 16 + l4 * 4];
      u16x4 r0 = *(const u16x4*)sp0;
      u16x4 r1 = *(const u16x4*)sp1;
      float e00 = __expf(bf2f(r0[0]) - m0);
      float e01 = __expf(bf2f(r0[1]) - m0);
      float e02 = __expf(bf2f(r0[2]) - m0);
      float e03 = __expf(bf2f(r0[3]) - m0);
      float e10 = __expf(bf2f(r1[0]) - m1);
      float e11 = __expf(bf2f(r1[1]) - m1);
      float e12 = __expf(bf2f(r1[2]) - m1);
      float e13 = __expf(bf2f(r1[3]) - m1);
      ps0 += (e00 + e01) + (e02 + e03);
      ps1 += (e10 + e11) + (e12 + e13);
      uint2 k0, k1;
      k0.x = pk_bf16(e00, e01);
      k0.y = pk_bf16(e02, e03);
      k1.x = pk_bf16(e10, e11);
      k1.y = pk_bf16(e12, e13);
      *(uint2*)sp0 = k0;
      *(uint2*)sp1 = k1;
    }
    ps0 += __shfl_xor(ps0, 16);
    ps0 += __shfl_xor(ps0, 32);
    ps1 += __shfl_xor(ps1, 16);
    ps1 += __shfl_xor(ps1, 32);
    if (l < 16) {
      RedSM[tm][l][w4] = make_float2(m0, ps0);
      RedSM[tm][16 + l][w4] = make_float2(m1, ps1);
    }
    __syncthreads();  // B: e-values + RedSM visible

    // ---- P3: PV with per-segment accumulators ----
    // amean scales for row l15 (q-group qgw), segments dtw*2 and dtw*2+1:
    float Mq = RedSM[tm][qgw * 16 + l15][0].x;
#pragma unroll
    for (int j = 1; j < 8; ++j) Mq = fmaxf(Mq, RedSM[tm][qgw * 16 + l15][j].x);
    float Lq = 0.f;
#pragma unroll
    for (int j = 0; j < 8; ++j) {
      float2 v = RedSM[tm][qgw * 16 + l15][j];
      Lq += v.y * __expf(v.x - Mq);
    }
    const float sA = __expf(RedSM[tm][qgw * 16 + l15][dtw * 2].x - Mq) / Lq * 0.0625f;
    const float sB = __expf(RedSM[tm][qgw * 16 + l15][dtw * 2 + 1].x - Mq) / Lq * 0.0625f;

    f32x4 ys[8] = {};
    const unsigned short* vb =
        Vt + (size_t)((b * 16 + h) * 64 + dtw * 16 + l15) * 1024 + l4 * 8;
    __builtin_amdgcn_s_setprio(1);
#pragma unroll
    for (int kq = 0; kq < 4; ++kq) {
#pragma unroll
      for (int kk = 0; kk < 8; ++kk) {
        const int ks = kq * 8 + kk;
        const int seg = kq * 2 + (kk >> 2);  // compile-time per unrolled iter
        s16x8 pa = *(const s16x8*)&S2[tm][(qgw * 16 + l15) * STR + ks * 32 + l4 * 8];
        ys[seg] =
            __builtin_amdgcn_mfma_f32_16x16x32_bf16(pa, *(const s16x8*)(vb + ks * 32), ys[seg], 0, 0, 0);
        if (kq == dtw) {  // wave-uniform; static amean indices
          const float fac = (kk < 4) ? sA : sB;
#pragma unroll
          for (int e2 = 0; e2 < 4; ++e2) {
            float2 fv;
            fv.x = bf2f((unsigned short)pa[e2 * 2]) * fac;
            fv.y = bf2f((unsigned short)pa[e2 * 2 + 1]) * fac;
            am[kk * 4 + e2] = __hadd2(am[kk * 4 + e2], __float22half2_rn(fv));
          }
        }
      }
    }
    __builtin_amdgcn_s_setprio(0);
    // y(row) = sum_w ys[w] * e^(m_w - M_row) / L_row   (exact softmax)
#pragma unroll
    for (int rr = 0; rr < 4; ++rr) {
      const int row = qgw * 16 + l4 * 4 + rr;
      float M = RedSM[tm][row][0].x;
#pragma unroll
      for (int j = 1; j < 8; ++j) M = fmaxf(M, RedSM[tm][row][j].x);
      float L = 0.f, acc = 0.f;
#pragma unroll
      for (int j = 0; j < 8; ++j) {
        float2 v = RedSM[tm][row][j];
        float sc = __expf(v.x - M);
        L += v.y * sc;
        acc += ys[j][rr] * sc;
      }
      Ybf[(size_t)(b * 1024 + q0 + row) * 1024 + h * 64 + dtw * 16 + l15] = f2bf(acc / L);
    }
    __syncthreads();  // E: S2/RedSM reuse next iteration
  }

  // ---- cross-team amean reduce (fp32 add of fp16 partials) + Pmean write ----
  unsigned int* us = (unsigned int*)S2;  // 512 thr * 32 uints = 64KB < S2[0] (66KB)
  if (tm == 1) {
#pragma unroll
    for (int j = 0; j < 32; ++j) us[ttid * 32 + j] = __builtin_bit_cast(unsigned int, am[j]);
  }
  __syncthreads();
  if (tm == 0) {
    unsigned short* pm = Pmean + ((size_t)(b * 2 + hg) << 20) +
                         (size_t)(q0 + qgw * 16 + l15) * 1024 + dtw * 256 + l4 * 8;
#pragma unroll
    for (int kk = 0; kk < 8; ++kk) {
      s16x8 ov;
#pragma unroll
      for (int e2 = 0; e2 < 4; ++e2) {
        int j = kk * 4 + e2;
        __half2 ot = __builtin_bit_cast(__half2, us[ttid * 32 + j]);
        float2 fo = __half22float2(ot);
        float2 fm = __half22float2(am[j]);
        ov[e2 * 2] = (short)f2bf(fm.x + fo.x);
        ov[e2 * 2 + 1] = (short)f2bf(fm.y + fo.y);
      }
      *(s16x8*)&pm[kk * 32] = ov;
    }
  }
}

// ---------------- attm = partial[hg0] + partial[hg1] (fp32 out) ----------------
__global__ __launch_bounds__(256) void mean2(const unsigned short* __restrict__ P2,
                                             float* __restrict__ out) {
  size_t f = ((size_t)blockIdx.x * 256 + threadIdx.x) * 8;
  int b = (int)(f >> 20);
  size_t i0 = f + ((size_t)b << 20);
  s16x8 a = *(const s16x8*)&P2[i0];
  s16x8 d = *(const s16x8*)&P2[i0 + (1u << 20)];
  float4 o0, o1;
  o0.x = bf2f((unsigned short)a[0]) + bf2f((unsigned short)d[0]);
  o0.y = bf2f((unsigned short)a[1]) + bf2f((unsigned short)d[1]);
  o0.z = bf2f((unsigned short)a[2]) + bf2f((unsigned short)d[2]);
  o0.w = bf2f((unsigned short)a[3]) + bf2f((unsigned short)d[3]);
  o1.x = bf2f((unsigned short)a[4]) + bf2f((unsigned short)d[4]);
  o1.y = bf2f((unsigned short)a[5]) + bf2f((unsigned short)d[5]);
  o1.z = bf2f((unsigned short)a[6]) + bf2f((unsigned short)d[6]);
  o1.w = bf2f((unsigned short)a[7]) + bf2f((unsigned short)d[7]);
  *(float4*)&out[f] = o0;
  *(float4*)&out[f + 4] = o1;
}

// ---------------------------------------------------------------------------
extern "C" void kernel_launch(void* const* d_in, const int* in_sizes, int n_in, void* d_out,
                              int out_size, void* d_ws, size_t ws_size, hipStream_t stream) {
  const float* q_in = (const float*)d_in[0];
  const float* k_in = (const float*)d_in[1];
  const float* v_in = (const float*)d_in[2];
  const float* Wq = (const float*)d_in[3];
  const float* bq = (const float*)d_in[4];
  const float* Wk = (const float*)d_in[5];
  const float* bk = (const float*)d_in[6];
  const float* Wv = (const float*)d_in[7];
  const float* bv = (const float*)d_in[8];
  const float* Wo = (const float*)d_in[9];
  const float* bo = (const float*)d_in[10];

  float* out_y = (float*)d_out;
  float* out_att = out_y + (size_t)BT * N_EMBD;

  char* ws = (char*)d_ws;
  const size_t MB = 1024 * 1024;
  unsigned short* xin_bf = (unsigned short*)(ws);           // 3 x 8MB (q,k,v inputs bf16)
  unsigned short* W_bf = (unsigned short*)(ws + 24 * MB);   // Wo,Wq,Wk,Wv bf16
  unsigned short* Qp = (unsigned short*)(ws + 32 * MB);
  unsigned short* Kp = Qp + (size_t)BT * N_EMBD;
  unsigned short* Vp = Kp + (size_t)BT * N_EMBD;
  unsigned short* Pmean = (unsigned short*)(ws);            // [b][2][1024][1024] bf16 (16MB)
  unsigned short* Vt = (unsigned short*)(ws + 16 * MB);     // over dead v xin
  unsigned short* Ybf = Vp;                                 // over dead Vp (after transpose_v)

  const int NIN = BT * N_EMBD;     // 4M
  const int NW = N_EMBD * N_EMBD;  // 1M

  cvt_in3<<<dim3(NIN / 1024, 1, 3), 256, 0, stream>>>(q_in, k_in, v_in, xin_bf);
  cvt_w4<<<dim3(NW / 1024, 1, 4), 256, 0, stream>>>(Wo, Wq, Wk, Wv, W_bf);

  gemm_qkv<<<dim3(BT / 128, N_EMBD / 128, 3), 256, 0, stream>>>(xin_bf, W_bf, bq, bk, bv, Qp);
  transpose_v<<<dim3(16, 16, 4), 256, 0, stream>>>(Vp, Vt);
  attn_ph2<<<256, 1024, 0, stream>>>(Qp, Kp, Vt, Ybf, Pmean);
  mean2<<<2048, 256, 0, stream>>>(Pmean, out_att);
  gemm_out<<<dim3(BT / 128, N_EMBD / 128), 256, 0, stream>>>(Ybf, W_bf, bo, out_y);
}